// Round 1
// baseline (437.066 us; speedup 1.0000x reference)
//
#include <hip/hip_runtime.h>

typedef __attribute__((ext_vector_type(8))) short short8;
typedef __attribute__((ext_vector_type(8))) unsigned short ushort8;
typedef __attribute__((ext_vector_type(4))) float f32x4;

__device__ __forceinline__ unsigned short f2bf(float f) {
  unsigned int u = __float_as_uint(f);
  u += 0x7fffu + ((u >> 16) & 1u);   // round-to-nearest-even
  return (unsigned short)(u >> 16);
}

__device__ __forceinline__ void gl_lds16(const void* g, void* l) {
  __builtin_amdgcn_global_load_lds(
      (const __attribute__((address_space(1))) unsigned int*)g,
      (__attribute__((address_space(3))) unsigned int*)l, 16, 0, 0);
}

// ---- prep: z (f32) -> bf16 ----
__global__ void convert_z(const float* __restrict__ z, unsigned short* __restrict__ zbf, int n8) {
  int i = blockIdx.x * 256 + threadIdx.x;
  if (i < n8) {
    const float* p = z + (size_t)i * 8;
    f32x4 a = *(const f32x4*)p;
    f32x4 c = *(const f32x4*)(p + 4);
    ushort8 o;
    o[0]=f2bf(a[0]); o[1]=f2bf(a[1]); o[2]=f2bf(a[2]); o[3]=f2bf(a[3]);
    o[4]=f2bf(c[0]); o[5]=f2bf(c[1]); o[6]=f2bf(c[2]); o[7]=f2bf(c[3]);
    *(ushort8*)(zbf + (size_t)i * 8) = o;
  }
}

// ---- prep: W1 [544,128] f32 -> W1T [128,544] bf16 ----
__global__ void make_w1t(const float* __restrict__ W1, unsigned short* __restrict__ W1T) {
  int idx = blockIdx.x * 256 + threadIdx.x;   // idx = k*128 + n
  if (idx < 544 * 128) {
    int n = idx & 127, k = idx >> 7;
    W1T[(size_t)n * 544 + k] = f2bf(W1[idx]);
  }
}

// ---- main: 128 edges x 128 hidden per block, 4 waves (2x2), K=17 steps of 32 ----
template<bool ZBF16>
__global__ __launch_bounds__(256, 2) void edge_mlp(
    const float* __restrict__ z, const unsigned short* __restrict__ zbf,
    const int* __restrict__ eidx, const float* __restrict__ ea,
    const unsigned short* __restrict__ W1T,
    const float* __restrict__ b1, const float* __restrict__ W2,
    const float* __restrict__ b2, float* __restrict__ out, int E)
{
  __shared__ unsigned short As[2][128 * 32];   // [row][k] 64B rows
  __shared__ unsigned short Bs[2][128 * 32];   // [n][k]   64B rows
  __shared__ float part[128][2];

  const int tid  = threadIdx.x;
  const int wid  = tid >> 6;
  const int lane = tid & 63;
  const int wrow = wid >> 1, wcol = wid & 1;
  const int quad = lane >> 4, l15 = lane & 15;
  const int lrow = lane >> 2, lch = lane & 3;

  // two staging rows per thread (instr groups 2*wid and 2*wid+1)
  const int r0 = 32 * wid + lrow;
  const int r1 = r0 + 16;
  int e0 = blockIdx.x * 128 + r0; if (e0 >= E) e0 = E - 1;
  int e1 = blockIdx.x * 128 + r1; if (e1 >= E) e1 = E - 1;
  const int s0 = eidx[e0], d0 = eidx[E + e0];
  const int s1 = eidx[e1], d1 = eidx[E + e1];

  const unsigned short* zr[4];
  const float* zrf[4];
  if constexpr (ZBF16) {
    zr[0] = zbf + (size_t)s0 * 256; zr[1] = zbf + (size_t)d0 * 256;
    zr[2] = zbf + (size_t)s1 * 256; zr[3] = zbf + (size_t)d1 * 256;
  } else {
    zrf[0] = z + (size_t)s0 * 256; zrf[1] = z + (size_t)d0 * 256;
    zrf[2] = z + (size_t)s1 * 256; zrf[3] = z + (size_t)d1 * 256;
  }
  const float* eap[2] = { ea + (size_t)e0 * 32, ea + (size_t)e1 * 32 };

  f32x4 acc[4][4] = {};

  auto stage = [&](int ks, int b) {
    // B tile: rows n, cols [ks*32, ks*32+32) of W1T
#pragma unroll
    for (int j = 0; j < 2; ++j) {
      int nb = 2 * wid + j;
      const unsigned short* g = W1T + (size_t)(nb * 16 + lrow) * 544 + ks * 32 + lch * 8;
      gl_lds16(g, &Bs[b][nb * 512]);
    }
    if (ks < 16) {
      if constexpr (ZBF16) {
#pragma unroll
        for (int j = 0; j < 2; ++j) {
          const unsigned short* g =
              (ks < 8 ? zr[2 * j] + ks * 32 : zr[2 * j + 1] + (ks - 8) * 32) + lch * 8;
          gl_lds16(g, &As[b][(2 * wid + j) * 512]);
        }
      } else {
#pragma unroll
        for (int j = 0; j < 2; ++j) {
          const float* g =
              (ks < 8 ? zrf[2 * j] + ks * 32 : zrf[2 * j + 1] + (ks - 8) * 32) + lch * 8;
          f32x4 a = *(const f32x4*)g;
          f32x4 c = *(const f32x4*)(g + 4);
          ushort8 o;
          o[0]=f2bf(a[0]); o[1]=f2bf(a[1]); o[2]=f2bf(a[2]); o[3]=f2bf(a[3]);
          o[4]=f2bf(c[0]); o[5]=f2bf(c[1]); o[6]=f2bf(c[2]); o[7]=f2bf(c[3]);
          int r = (j == 0) ? r0 : r1;
          *(ushort8*)&As[b][r * 32 + lch * 8] = o;
        }
      }
    } else {
      // edge_attr chunk (k 512..543), f32 -> bf16 via registers
#pragma unroll
      for (int j = 0; j < 2; ++j) {
        const float* g = eap[j] + lch * 8;
        f32x4 a = *(const f32x4*)g;
        f32x4 c = *(const f32x4*)(g + 4);
        ushort8 o;
        o[0]=f2bf(a[0]); o[1]=f2bf(a[1]); o[2]=f2bf(a[2]); o[3]=f2bf(a[3]);
        o[4]=f2bf(c[0]); o[5]=f2bf(c[1]); o[6]=f2bf(c[2]); o[7]=f2bf(c[3]);
        int r = (j == 0) ? r0 : r1;
        *(ushort8*)&As[b][r * 32 + lch * 8] = o;
      }
    }
  };

  auto compute = [&](int b) {
    short8 af[4], bfv[4];
#pragma unroll
    for (int i = 0; i < 4; ++i) {
      af[i]  = *(const short8*)&As[b][(wrow * 64 + i * 16 + l15) * 32 + quad * 8];
      bfv[i] = *(const short8*)&Bs[b][(wcol * 64 + i * 16 + l15) * 32 + quad * 8];
    }
#pragma unroll
    for (int mi = 0; mi < 4; ++mi)
#pragma unroll
      for (int ni = 0; ni < 4; ++ni)
        acc[mi][ni] = __builtin_amdgcn_mfma_f32_16x16x32_bf16(af[mi], bfv[ni], acc[mi][ni], 0, 0, 0);
  };

  stage(0, 0);
  for (int s = 0; s < 17; ++s) {
    __syncthreads();
    if (s + 1 < 17) stage(s + 1, (s + 1) & 1);
    compute(s & 1);
  }

  // epilogue: h = relu(acc + b1), out = h . W2 + b2
  float b1v[4], w2v[4];
#pragma unroll
  for (int ni = 0; ni < 4; ++ni) {
    int col = wcol * 64 + ni * 16 + l15;
    b1v[ni] = b1[col];
    w2v[ni] = W2[col];
  }
#pragma unroll
  for (int mi = 0; mi < 4; ++mi) {
#pragma unroll
    for (int r = 0; r < 4; ++r) {
      float p = 0.f;
#pragma unroll
      for (int ni = 0; ni < 4; ++ni) {
        float h = acc[mi][ni][r] + b1v[ni];
        h = fmaxf(h, 0.f);
        p = fmaf(h, w2v[ni], p);
      }
#pragma unroll
      for (int off = 8; off; off >>= 1) p += __shfl_xor(p, off);
      if (l15 == 0) part[wrow * 64 + mi * 16 + quad * 4 + r][wcol] = p;
    }
  }
  __syncthreads();
  if (tid < 128) {
    int e = blockIdx.x * 128 + tid;
    if (e < E) out[e] = part[tid][0] + part[tid][1] + b2[0];
  }
}

extern "C" void kernel_launch(void* const* d_in, const int* in_sizes, int n_in,
                              void* d_out, int out_size, void* d_ws, size_t ws_size,
                              hipStream_t stream) {
  const float* z   = (const float*)d_in[0];
  const int*   eix = (const int*)d_in[1];
  const float* ea  = (const float*)d_in[2];
  const float* W1  = (const float*)d_in[3];
  const float* b1  = (const float*)d_in[4];
  const float* W2  = (const float*)d_in[5];
  const float* b2  = (const float*)d_in[6];
  float* out = (float*)d_out;

  const int E  = in_sizes[1] / 2;     // edge_label_index is [2, E]
  const int NN = in_sizes[0] / 256;   // nodes

  unsigned short* wsp = (unsigned short*)d_ws;
  const size_t zbytes = (size_t)NN * 512;                 // bf16 z
  const size_t w1t_bytes = 544 * 128 * 2;
  const bool use_zbf = ws_size >= zbytes + w1t_bytes + 64;
  unsigned short* zbf = wsp;
  unsigned short* W1T = use_zbf ? (wsp + (size_t)NN * 256) : wsp;

  make_w1t<<<272, 256, 0, stream>>>(W1, W1T);
  if (use_zbf) {
    int n8 = NN * 256 / 8;
    convert_z<<<(n8 + 255) / 256, 256, 0, stream>>>(z, zbf, n8);
  }

  int grid = (E + 127) / 128;
  if (use_zbf)
    edge_mlp<true><<<grid, 256, 0, stream>>>(z, zbf, eix, ea, W1T, b1, W2, b2, out, E);
  else
    edge_mlp<false><<<grid, 256, 0, stream>>>(z, zbf, eix, ea, W1T, b1, W2, b2, out, E);
}

// Round 2
// 346.403 us; speedup vs baseline: 1.2617x; 1.2617x over previous
//
#include <hip/hip_runtime.h>

typedef __attribute__((ext_vector_type(8))) short short8;
typedef __attribute__((ext_vector_type(8))) unsigned short ushort8;
typedef __attribute__((ext_vector_type(4))) unsigned short ushort4v;
typedef __attribute__((ext_vector_type(4))) float f32x4;

__device__ __forceinline__ unsigned short f2bf(float f) {
  unsigned int u = __float_as_uint(f);
  u += 0x7fffu + ((u >> 16) & 1u);   // round-to-nearest-even
  return (unsigned short)(u >> 16);
}
__device__ __forceinline__ float bf2f(unsigned short u) {
  return __uint_as_float(((unsigned int)u) << 16);
}
__device__ __forceinline__ void gl_lds16(const void* g, void* l) {
  __builtin_amdgcn_global_load_lds(
      (const __attribute__((address_space(1))) unsigned int*)g,
      (__attribute__((address_space(3))) unsigned int*)l, 16, 0, 0);
}

// ---- prep: W1T2 [256 n'][256 k] bf16 (n'<128: W1a cols, n'>=128: W1b cols),
// ----       W1cT [128 n][32 k] bf16 (edge_attr weight, transposed)
__global__ void prep_weights(const float* __restrict__ W1,
                             unsigned short* __restrict__ W1T2,
                             unsigned short* __restrict__ W1cT) {
  int idx = blockIdx.x * 256 + threadIdx.x;
  if (idx < 65536) {
    int np = idx >> 8, k = idx & 255;
    W1T2[idx] = f2bf(W1[(size_t)(k + ((np >> 7) << 8)) * 128 + (np & 127)]);
  } else if (idx < 65536 + 4096) {
    int j = idx - 65536;
    int n = j >> 5, k = j & 31;
    W1cT[j] = f2bf(W1[(size_t)(512 + k) * 128 + n]);
  }
}

// ---- node projection: Ps[node][256] bf16, column-swizzled within each 128-half:
// ---- stored index c' = (c&15)*8 + (c>>4)
__global__ __launch_bounds__(256) void node_proj(
    const float* __restrict__ z, const unsigned short* __restrict__ W1T2,
    unsigned short* __restrict__ Ps, int NN) {
  __shared__ unsigned short As[2][128 * 32];
  __shared__ unsigned short Bs[2][128 * 32];
  const int tid = threadIdx.x, wid = tid >> 6, lane = tid & 63;
  const int wrow = wid >> 1, wcol = wid & 1;
  const int quad = lane >> 4, l15 = lane & 15;
  const int lrow = lane >> 2, lch = lane & 3;
  const int bm = blockIdx.x, half = blockIdx.y;

  const int r0 = 32 * wid + lrow, r1 = r0 + 16;
  const int m0 = min(bm * 128 + r0, NN - 1);
  const int m1 = min(bm * 128 + r1, NN - 1);
  const float* a0 = z + (size_t)m0 * 256;
  const float* a1 = z + (size_t)m1 * 256;

  f32x4 acc[4][4] = {};

  auto stage = [&](int ks, int b) {
#pragma unroll
    for (int j = 0; j < 2; ++j) {
      int nb = 2 * wid + j;
      const unsigned short* g =
          W1T2 + (size_t)(half * 128 + nb * 16 + lrow) * 256 + ks * 32 + lch * 8;
      gl_lds16(g, &Bs[b][nb * 512]);
    }
#pragma unroll
    for (int j = 0; j < 2; ++j) {
      const float* g = (j ? a1 : a0) + ks * 32 + lch * 8;
      f32x4 a = *(const f32x4*)g;
      f32x4 c = *(const f32x4*)(g + 4);
      ushort8 o;
      o[0]=f2bf(a[0]); o[1]=f2bf(a[1]); o[2]=f2bf(a[2]); o[3]=f2bf(a[3]);
      o[4]=f2bf(c[0]); o[5]=f2bf(c[1]); o[6]=f2bf(c[2]); o[7]=f2bf(c[3]);
      *(ushort8*)&As[b][(j ? r1 : r0) * 32 + lch * 8] = o;
    }
  };

  auto compute = [&](int b) {
    short8 af[4], bfv[4];
#pragma unroll
    for (int i = 0; i < 4; ++i) {
      af[i]  = *(const short8*)&As[b][(wrow * 64 + i * 16 + l15) * 32 + quad * 8];
      bfv[i] = *(const short8*)&Bs[b][(wcol * 64 + i * 16 + l15) * 32 + quad * 8];
    }
#pragma unroll
    for (int mi = 0; mi < 4; ++mi)
#pragma unroll
      for (int ni = 0; ni < 4; ++ni)
        acc[mi][ni] = __builtin_amdgcn_mfma_f32_16x16x32_bf16(af[mi], bfv[ni], acc[mi][ni], 0, 0, 0);
  };

  stage(0, 0);
#pragma unroll
  for (int s = 0; s < 8; ++s) {
    __syncthreads();
    if (s + 1 < 8) stage(s + 1, (s + 1) & 1);
    compute(s & 1);
  }

  // epilogue: store bf16, column-swizzled: col c = wcol*64+ni*16+l15 -> c' = l15*8 + wcol*4 + ni
#pragma unroll
  for (int mi = 0; mi < 4; ++mi) {
#pragma unroll
    for (int r = 0; r < 4; ++r) {
      int row = wrow * 64 + mi * 16 + quad * 4 + r;
      int node = bm * 128 + row;
      if (node < NN) {
        ushort4v o;
#pragma unroll
        for (int ni = 0; ni < 4; ++ni) o[ni] = f2bf(acc[mi][ni][r]);
        *(ushort4v*)&Ps[(size_t)node * 256 + half * 128 + l15 * 8 + wcol * 4] = o;
      }
    }
  }
}

// ---- edge kernel: out[e] = relu(P1[src] + P2[dst] + ea@W1c + b1) . W2 + b2
// ---- 128 edges/block, 4 waves x (32 edges x 128 hidden), K=32 single MFMA pass
__global__ __launch_bounds__(256) void edge_pred(
    const int* __restrict__ eidx, const float* __restrict__ ea,
    const unsigned short* __restrict__ Ps, const unsigned short* __restrict__ W1cT,
    const float* __restrict__ b1, const float* __restrict__ W2,
    const float* __restrict__ b2, float* __restrict__ out, int E) {
  __shared__ unsigned short EaS[128 * 32];
  __shared__ unsigned short WcS[128 * 32];
  const int tid = threadIdx.x, wid = tid >> 6, lane = tid & 63;
  const int quad = lane >> 4, l15 = lane & 15;
  const int lrow = lane >> 2, lch = lane & 3;
  const int be = blockIdx.x * 128;

  // stage W1cT -> LDS (async, 2 instr/wave, fully coalesced)
#pragma unroll
  for (int j = 0; j < 2; ++j) {
    int nb = 2 * wid + j;
    gl_lds16(W1cT + (size_t)(nb * 16 + lrow) * 32 + lch * 8, &WcS[nb * 512]);
  }

  // stage ea (f32 -> bf16) : each thread 16 floats = half an edge row
  {
    int e_loc = tid >> 1, part = tid & 1;
    size_t e_g = (size_t)min(be + e_loc, E - 1);
    const float* g = ea + e_g * 32 + part * 16;
    f32x4 a = *(const f32x4*)g;
    f32x4 b = *(const f32x4*)(g + 4);
    f32x4 c = *(const f32x4*)(g + 8);
    f32x4 d = *(const f32x4*)(g + 12);
    ushort8 o1, o2;
    o1[0]=f2bf(a[0]); o1[1]=f2bf(a[1]); o1[2]=f2bf(a[2]); o1[3]=f2bf(a[3]);
    o1[4]=f2bf(b[0]); o1[5]=f2bf(b[1]); o1[6]=f2bf(b[2]); o1[7]=f2bf(b[3]);
    o2[0]=f2bf(c[0]); o2[1]=f2bf(c[1]); o2[2]=f2bf(c[2]); o2[3]=f2bf(c[3]);
    o2[4]=f2bf(d[0]); o2[5]=f2bf(d[1]); o2[6]=f2bf(d[2]); o2[7]=f2bf(d[3]);
    *(ushort8*)&EaS[e_loc * 32 + part * 16] = o1;
    *(ushort8*)&EaS[e_loc * 32 + part * 16 + 8] = o2;
  }

  // issue P gathers early (latency overlaps staging + MFMA)
  int srcn[8], dstn[8];
#pragma unroll
  for (int mi = 0; mi < 2; ++mi)
#pragma unroll
    for (int r = 0; r < 4; ++r) {
      int t = mi * 4 + r;
      int ec = min(be + wid * 32 + mi * 16 + quad * 4 + r, E - 1);
      srcn[t] = eidx[ec];
      dstn[t] = eidx[E + ec];
    }
  short8 p1[8], p2[8];
#pragma unroll
  for (int t = 0; t < 8; ++t) {
    p1[t] = *(const short8*)&Ps[(size_t)srcn[t] * 256 + l15 * 8];
    p2[t] = *(const short8*)&Ps[(size_t)dstn[t] * 256 + 128 + l15 * 8];
  }

  __syncthreads();

  short8 af[2], bfv[8];
#pragma unroll
  for (int mi = 0; mi < 2; ++mi)
    af[mi] = *(const short8*)&EaS[(wid * 32 + mi * 16 + l15) * 32 + quad * 8];
#pragma unroll
  for (int ni = 0; ni < 8; ++ni)
    bfv[ni] = *(const short8*)&WcS[(ni * 16 + l15) * 32 + quad * 8];

  f32x4 acc[2][8] = {};
#pragma unroll
  for (int mi = 0; mi < 2; ++mi)
#pragma unroll
    for (int ni = 0; ni < 8; ++ni)
      acc[mi][ni] = __builtin_amdgcn_mfma_f32_16x16x32_bf16(af[mi], bfv[ni], acc[mi][ni], 0, 0, 0);

  float b1v[8], w2v[8];
#pragma unroll
  for (int ni = 0; ni < 8; ++ni) {
    int c = ni * 16 + l15;
    b1v[ni] = b1[c];
    w2v[ni] = W2[c];
  }
  const float b2v = b2[0];

#pragma unroll
  for (int mi = 0; mi < 2; ++mi) {
#pragma unroll
    for (int r = 0; r < 4; ++r) {
      int t = mi * 4 + r;
      float p = 0.f;
#pragma unroll
      for (int ni = 0; ni < 8; ++ni) {
        float s = bf2f((unsigned short)p1[t][ni]) + bf2f((unsigned short)p2[t][ni]);
        float h = acc[mi][ni][r] + s + b1v[ni];
        h = fmaxf(h, 0.f);
        p = fmaf(h, w2v[ni], p);
      }
      p += __shfl_xor(p, 1);
      p += __shfl_xor(p, 2);
      p += __shfl_xor(p, 4);
      p += __shfl_xor(p, 8);
      int e = be + wid * 32 + mi * 16 + quad * 4 + r;
      if (l15 == 0 && e < E) out[e] = p + b2v;
    }
  }
}

extern "C" void kernel_launch(void* const* d_in, const int* in_sizes, int n_in,
                              void* d_out, int out_size, void* d_ws, size_t ws_size,
                              hipStream_t stream) {
  const float* z   = (const float*)d_in[0];
  const int*   eix = (const int*)d_in[1];
  const float* ea  = (const float*)d_in[2];
  const float* W1  = (const float*)d_in[3];
  const float* b1  = (const float*)d_in[4];
  const float* W2  = (const float*)d_in[5];
  const float* b2  = (const float*)d_in[6];
  float* out = (float*)d_out;

  const int E  = in_sizes[1] / 2;     // edge_label_index is [2, E]
  const int NN = in_sizes[0] / 256;   // nodes

  unsigned short* wsp = (unsigned short*)d_ws;
  unsigned short* Ps   = wsp;                               // NN*256 bf16 (51.2 MB)
  unsigned short* W1T2 = wsp + (size_t)NN * 256;            // 256*256 bf16
  unsigned short* W1cT = W1T2 + 65536;                      // 128*32 bf16

  prep_weights<<<273, 256, 0, stream>>>(W1, W1T2, W1cT);

  dim3 gp((NN + 127) / 128, 2);
  node_proj<<<gp, 256, 0, stream>>>(z, W1T2, Ps, NN);

  int ge = (E + 127) / 128;
  edge_pred<<<ge, 256, 0, stream>>>(eix, ea, Ps, W1cT, b1, W2, b2, out, E);
}